// Round 4
// baseline (87.222 us; speedup 1.0000x reference)
//
#include <hip/hip_runtime.h>
#include <hip/hip_bf16.h>
#include <math.h>

#define NCLS 151
#define NQ   100
#define NB   2
#define HW   16384   // 128*128
#define NCO  150     // classes after dropping class 0
#define OUTW 512
#define KPAD 128     // Q padded to 128
#define CPAD 160     // C padded to 160
#define CBLK 32      // classes per block (5 c-splits)
#define AROW 136     // s_a row stride in ushort (272 B)
#define SROW 130     // s_seg row stride in float

using short8 = __attribute__((ext_vector_type(8))) short;
using f32x4  = __attribute__((ext_vector_type(4))) float;

static __device__ __forceinline__ ushort f2bf(float x) {
    union { float f; unsigned u; } v; v.f = x;
    unsigned r = v.u + 0x7fff + ((v.u >> 16) & 1);   // RNE
    return (ushort)(r >> 16);
}

// ---------------- Kernel 1: softmax -> transposed bf16 scores A[b][c][q] ----------------
__global__ __launch_bounds__(64) void softmax_k(const float* __restrict__ logits,
                                                ushort* __restrict__ scoresT) {
    int q = blockIdx.x & 127;
    int b = blockIdx.x >> 7;
    int lane = threadIdx.x;
    ushort* A = scoresT + (size_t)b * CPAD * KPAD;

    if (q >= NQ) {   // zero pad columns q in [100,128)
        A[lane * KPAD + q] = 0;
        A[(lane + 64) * KPAD + q] = 0;
        if (lane < 32) A[(lane + 128) * KPAD + q] = 0;
        return;
    }

    const float* in = logits + (size_t)(b * NQ + q) * NCLS;
    float v0 = in[lane];
    float v1 = in[lane + 64];
    float v2 = (lane < NCLS - 128) ? in[lane + 128] : -1e30f;

    float m = fmaxf(fmaxf(v0, v1), v2);
    #pragma unroll
    for (int o = 32; o; o >>= 1) m = fmaxf(m, __shfl_xor(m, o));

    float e0 = __expf(v0 - m);
    float e1 = __expf(v1 - m);
    float e2 = (lane < NCLS - 128) ? __expf(v2 - m) : 0.f;

    float s = e0 + e1 + e2;
    #pragma unroll
    for (int o = 32; o; o >>= 1) s += __shfl_xor(s, o);

    float inv = 1.f / s;
    if (lane >= 1) A[(lane - 1) * KPAD + q] = f2bf(e0 * inv);
    A[(lane + 63) * KPAD + q] = f2bf(e1 * inv);
    if (lane < 23)       A[(lane + 127) * KPAD + q] = f2bf(e2 * inv);
    else if (lane < 33)  A[(lane + 127) * KPAD + q] = 0;   // c-pad rows
}

// ---------------- Kernel 2: sigmoid + transpose masks -> BT[b][pix][128] bf16 ----------
// block 256 thr handles 256 pixels x all 128 (padded) q. grid (HW/256, NB).
__global__ __launch_bounds__(256) void sigt_k(const float* __restrict__ masks,
                                              ushort* __restrict__ BT) {
    __shared__ unsigned s32[256][65];   // 66,560 B; row stride 65 -> conflict-free

    int b = blockIdx.y;
    int pix0 = blockIdx.x * 256;
    int tid = threadIdx.x;

    #pragma unroll
    for (int d = 50; d < 64; ++d) s32[tid][d] = 0;   // q-pad 100..127

    const float* mb = masks + (size_t)b * NQ * HW + pix0;
    #pragma unroll 2
    for (int qp = 0; qp < 50; ++qp) {
        float x0 = mb[(size_t)(2 * qp) * HW + tid];
        float x1 = mb[(size_t)(2 * qp + 1) * HW + tid];
        unsigned lo = f2bf(1.f / (1.f + __expf(-x0)));
        unsigned hi = f2bf(1.f / (1.f + __expf(-x1)));
        s32[tid][qp] = lo | (hi << 16);
    }
    __syncthreads();

    unsigned* out32 = (unsigned*)(BT + ((size_t)b * HW + pix0) * KPAD);
    #pragma unroll
    for (int t = 0; t < 64; ++t) {
        int i = tid + t * 256;
        int p = i >> 6, d = i & 63;
        out32[p * 64 + d] = s32[p][d];
    }
}

// ---------------- Kernel 3: fused MFMA einsum + bilinear resize ----------------
// block 512 thr (8 waves); grid (128 row-pairs, NB*5 c-splits).
// B-fragments gathered straight from L2-resident BT (no B LDS tile).
__global__ __launch_bounds__(512, 6) void fused_k(const ushort* __restrict__ BT,
                                                  const ushort* __restrict__ scoresT,
                                                  float* __restrict__ out) {
    __shared__ __align__(16) ushort s_a[CBLK][AROW];    //  8,704 B
    __shared__ float s_seg[2][CBLK][SROW];              // 33,280 B

    int r   = blockIdx.x;
    int b   = blockIdx.y / 5;
    int cs  = blockIdx.y % 5;
    int tid = threadIdx.x;
    int r1  = min(r + 1, 127);
    int wid = tid >> 6, lane = tid & 63;
    int pr = lane & 15, kg = lane >> 4;

    // ---- stage A slice (32 c x 128 k bf16): exactly one float4 chunk per thread ----
    {
        const float4* src = (const float4*)(scoresT + (size_t)(b * CPAD + cs * CBLK) * KPAD);
        float4 v = src[tid];
        int c = tid >> 4, kc = tid & 15;
        *(float4*)&s_a[c][kc * 8] = v;
    }

    // ---- gather B fragments from global (pre-sigmoided, transposed, bf16) ----
    short8 bfr[2][2][2];   // [kc2][ks][nt]
    {
        int p0 = wid * 32 + pr;
        int p1 = p0 + 16;
        int gp0 = ((p0 < 128) ? r : r1) * 128 + (p0 & 127);
        int gp1 = ((p1 < 128) ? r : r1) * 128 + (p1 & 127);
        const ushort* B0 = BT + ((size_t)b * HW + gp0) * KPAD + kg * 8;
        const ushort* B1 = BT + ((size_t)b * HW + gp1) * KPAD + kg * 8;
        #pragma unroll
        for (int kc2 = 0; kc2 < 2; ++kc2)
            #pragma unroll
            for (int ks = 0; ks < 2; ++ks) {
                bfr[kc2][ks][0] = *(const short8*)(B0 + kc2 * 64 + ks * 32);
                bfr[kc2][ks][1] = *(const short8*)(B1 + kc2 * 64 + ks * 32);
            }
    }
    __syncthreads();

    // ---- MFMA: 4 k-steps x 2 c-tiles x 2 n-tiles ----
    f32x4 acc[2][2];
    #pragma unroll
    for (int ct = 0; ct < 2; ++ct)
        #pragma unroll
        for (int nt = 0; nt < 2; ++nt) acc[ct][nt] = (f32x4){0.f, 0.f, 0.f, 0.f};

    #pragma unroll
    for (int kc2 = 0; kc2 < 2; ++kc2)
        #pragma unroll
        for (int ks = 0; ks < 2; ++ks)
            #pragma unroll
            for (int ct = 0; ct < 2; ++ct) {
                short8 af = *(const short8*)&s_a[ct * 16 + pr][kc2 * 64 + ks * 32 + kg * 8];
                acc[ct][0] = __builtin_amdgcn_mfma_f32_16x16x32_bf16(af, bfr[kc2][ks][0], acc[ct][0], 0, 0, 0);
                acc[ct][1] = __builtin_amdgcn_mfma_f32_16x16x32_bf16(af, bfr[kc2][ks][1], acc[ct][1], 0, 0, 0);
            }

    // ---- acc -> s_seg (D layout: row = kg*4+j, col = pr) ----
    #pragma unroll
    for (int ct = 0; ct < 2; ++ct)
        #pragma unroll
        for (int nt = 0; nt < 2; ++nt) {
            int p = wid * 32 + nt * 16 + pr;
            int rs = p >> 7, px = p & 127;
            #pragma unroll
            for (int j = 0; j < 4; ++j) {
                int c = ct * 16 + kg * 4 + j;
                s_seg[rs][c][px] = acc[ct][nt][j];
            }
        }
    __syncthreads();

    // ---- emission: w-lerps once per (c,k), then NR h-row stores ----
    int cbase = cs * CBLK;
    for (int it = tid; it < CBLK * 128; it += 512) {
        int k = it & 127;
        int c = it >> 7;
        int cg = cbase + c;
        if (cg >= NCO) break;                 // wave-uniform
        int km = max(k - 1, 0), kp = min(k + 1, 127);
        const float* s0 = s_seg[0][c];
        const float* s1 = s_seg[1][c];
        float a0 = s0[km], a1 = s0[k], a2 = s0[kp];
        float b0 = s1[km], b1 = s1[k], b2 = s1[kp];

        float t0 = a0 + 0.625f * (a1 - a0);
        float t1 = a0 + 0.875f * (a1 - a0);
        float t2 = a1 + 0.125f * (a2 - a1);
        float t3 = a1 + 0.375f * (a2 - a1);
        float u0 = b0 + 0.625f * (b1 - b0);
        float u1 = b0 + 0.875f * (b1 - b0);
        float u2 = b1 + 0.125f * (b2 - b1);
        float u3 = b1 + 0.375f * (b2 - b1);

        float* op = out + (size_t)(b * NCO + cg) * (OUTW * OUTW) + 4 * k;

        if (r == 0) {                         // rows 0,1: clamped -> pure w-lerp
            float4 o; o.x = t0; o.y = t1; o.z = t2; o.w = t3;
            *(float4*)(op) = o;
            *(float4*)(op + OUTW) = o;
        }
        int nr = (r == 127) ? 2 : 4;
        #pragma unroll
        for (int ri = 0; ri < 4; ++ri) {
            if (ri >= nr) break;              // wave-uniform
            float fh = 0.125f + 0.25f * (float)ri;
            int h = 4 * r + 2 + ri;
            float4 o;
            o.x = t0 + fh * (u0 - t0);
            o.y = t1 + fh * (u1 - t1);
            o.z = t2 + fh * (u2 - t2);
            o.w = t3 + fh * (u3 - t3);
            *(float4*)(op + (size_t)h * OUTW) = o;
        }
    }
}

extern "C" void kernel_launch(void* const* d_in, const int* in_sizes, int n_in,
                              void* d_out, int out_size, void* d_ws, size_t ws_size,
                              hipStream_t stream) {
    const float* logits = (const float*)d_in[0];
    const float* masks  = (const float*)d_in[1];
    float* out = (float*)d_out;

    ushort* scoresT = (ushort*)d_ws;                      // 81,920 B
    ushort* BT      = (ushort*)((char*)d_ws + (1 << 17)); // 2*16384*128*2 = 8,388,608 B

    softmax_k<<<dim3(NB * 128), dim3(64), 0, stream>>>(logits, scoresT);
    sigt_k<<<dim3(HW / 256, NB), dim3(256), 0, stream>>>(masks, BT);
    fused_k<<<dim3(128, NB * 5), dim3(512), 0, stream>>>(BT, scoresT, out);
}